// Round 5
// baseline (5237.916 us; speedup 1.0000x reference)
//
#include <hip/hip_runtime.h>
#include <math.h>

#define NB 1000
#define NT 100
#define NI 264
#define NH 100
#define NO 264
#define NG 400          // 4*NH
#define EM 4            // encoder rows per block (250 blocks)
#define DM 8            // decoder rows per block (125 blocks per decoder)
#define DTH 704         // decoder threads: 0-399 gate, 400-663 fc, 664-703 idle

__device__ __forceinline__ float sigm(float x){ return 1.f / (1.f + __expf(-x)); }
__device__ __forceinline__ float tanh_fast(float x){
    float e = __expf(-2.f * x);
    return 2.f / (1.f + e) - 1.f;
}

// X-macro over the 25 float4 weight registers. Named scalars (w0..w24) are SSA
// values from the frontend: no alloca -> no SROA-ordering trap -> no scratch.
#define W_LIST(F) \
    F(0) F(1) F(2) F(3) F(4) F(5) F(6) F(7) F(8) F(9) \
    F(10) F(11) F(12) F(13) F(14) F(15) F(16) F(17) F(18) F(19) \
    F(20) F(21) F(22) F(23) F(24)

#define DECLW(q) float4 w##q;
#define LOADW(q) w##q = wsrc[q];

// NOTE: parameter names must not collide with member tokens (.x/.y/.z/.w)!
#define FMA4(acc, hv, wv) acc += hv.x*wv.x + hv.y*wv.y + hv.z*wv.z + hv.w*wv.w;

// ---------------- prep kernels ----------------

// Wih4[((k/4)*NG + n)*4 + (k&3)] = Wih[n*NI+k]  -> per-(k4,n) float4, coalesced dwordx4 loads
// bcat = bih + bhh
__global__ void prep_enc(const float* __restrict__ Wih,
                         const float* __restrict__ bih, const float* __restrict__ bhh,
                         float* __restrict__ Wih4, float* __restrict__ bcat)
{
    int idx = blockIdx.x * 256 + threadIdx.x;
    if (idx < NG * NI){
        int j  = idx & 3;
        int n  = (idx >> 2) % NG;
        int k4 = idx / (4 * NG);
        Wih4[idx] = Wih[n * NI + k4 * 4 + j];
    }
    if (idx < NG) bcat[idx] = bih[idx] + bhh[idx];
}

// Wdec[n][k] = Whh[n][k] + sum_o Wih[n][o] * fcW[o][k]   (decoder feedback folded in)
__global__ void prep_wdec(const float* __restrict__ Wih, const float* __restrict__ Whh,
                          const float* __restrict__ fcW, float* __restrict__ Wdec)
{
    int idx = blockIdx.x * 256 + threadIdx.x;
    if (idx >= NG * NH) return;
    int n = idx / NH, k = idx - n * NH;
    float acc = Whh[idx];
    const float* wr = Wih + (size_t)n * NI;
    for (int o = 0; o < NI; ++o) acc = fmaf(wr[o], fcW[o * NH + k], acc);
    Wdec[idx] = acc;
}

// b0 = bih+bhh ; bdec = b0 + Wih @ fcb ; zero the two loss accumulators
__global__ void prep_bias(const float* __restrict__ pb1, const float* __restrict__ pb2,
                          const float* __restrict__ pW,  const float* __restrict__ pfb,
                          const float* __restrict__ rb1, const float* __restrict__ rb2,
                          const float* __restrict__ rW,  const float* __restrict__ rfb,
                          float* __restrict__ b0_p, float* __restrict__ bdec_p,
                          float* __restrict__ b0_r, float* __restrict__ bdec_r,
                          float* __restrict__ loss)
{
    int tid = blockIdx.x * 256 + threadIdx.x;
    if (tid < 2) loss[tid] = 0.f;
    if (tid >= 2 * NG) return;
    int dd = tid / NG, n = tid - dd * NG;
    const float* b1 = dd ? rb1 : pb1;
    const float* b2 = dd ? rb2 : pb2;
    const float* W  = dd ? rW  : pW;
    const float* fb = dd ? rfb : pfb;
    float base = b1[n] + b2[n];
    float acc = base;
    const float* wr = W + (size_t)n * NI;
    for (int o = 0; o < NI; ++o) acc = fmaf(wr[o], fb[o], acc);
    if (dd){ b0_r[n] = base; bdec_r[n] = acc; }
    else   { b0_p[n] = base; bdec_p[n] = acc; }
}

// ---------------- encoder: Whh in named registers, streamed Wih4, 4 rows/block ----------------

__global__ __launch_bounds__(512, 1) void encoder_kernel(
    const float* __restrict__ src, const float* __restrict__ Wih4,
    const float* __restrict__ Whh, const float* __restrict__ bcat,
    float* __restrict__ h_out, float* __restrict__ c_out)
{
    __shared__ float sh_x[2][EM][NI];     // double-buffered x_t staging
    __shared__ float sh_h[EM][104];       // h (padded row stride)
    __shared__ float sh_g[NG][EM + 1];    // gates, stride 5 (gcd(5,32)=1, conflict-free)
    const int tid = threadIdx.x;
    const int m0  = blockIdx.x * EM;
    const bool act = tid < NG;
    const int n  = act ? tid : 0;
    const int mc = n / NH;
    const int jc = n % NH;

    // Whh row n in 25 named float4 registers (idle threads load row 0 harmlessly)
    const float4* wsrc = (const float4*)(Whh + (size_t)n * NH);
    W_LIST(DECLW)
    W_LIST(LOADW)
    float bias = 0.f;
    if (act){
        bias = bcat[n];
        sh_h[mc][jc] = 0.f;               // h0 = 0
    }
    float c_reg = 0.f, h_new = 0.f;
    const float*  s0 = src + (size_t)m0 * NT * NI;
    const float4* W4 = (const float4*)Wih4;

    // preload x_0 into buffer 0
    for (int i = tid; i < EM * NI; i += 512){
        int r = i / NI, k = i - r * NI;
        sh_x[0][r][k] = s0[(size_t)r * NT * NI + k];
    }
    __syncthreads();

    for (int t = 0; t < NT; ++t){
        const int cur = t & 1;
        // stage x_{t+1} into the other buffer (overlaps with gate compute below)
        if (t + 1 < NT){
            for (int i = tid; i < EM * NI; i += 512){
                int r = i / NI, k = i - r * NI;
                sh_x[cur ^ 1][r][k] = s0[(size_t)r * NT * NI + (size_t)(t + 1) * NI + k];
            }
        }
        if (act){
            float a0 = bias, a1 = bias, a2 = bias, a3 = bias;
            const float4* x0 = (const float4*)sh_x[cur][0];
            const float4* x1 = (const float4*)sh_x[cur][1];
            const float4* x2 = (const float4*)sh_x[cur][2];
            const float4* x3 = (const float4*)sh_x[cur][3];
            // x-projection: Wih4 streamed from L2 (one dwordx4/lane), x broadcast from LDS
            #pragma unroll 6
            for (int k4 = 0; k4 < NI / 4; ++k4){
                float4 wv = W4[k4 * NG + n];
                float4 xa = x0[k4]; FMA4(a0, xa, wv)
                float4 xb = x1[k4]; FMA4(a1, xb, wv)
                float4 xc = x2[k4]; FMA4(a2, xc, wv)
                float4 xd = x3[k4]; FMA4(a3, xd, wv)
            }
            // recurrent part: named-register weights, h broadcast from LDS
            #define EGROW(q) { float4 h_; \
                h_ = ((const float4*)sh_h[0])[q]; FMA4(a0, h_, w##q) \
                h_ = ((const float4*)sh_h[1])[q]; FMA4(a1, h_, w##q) \
                h_ = ((const float4*)sh_h[2])[q]; FMA4(a2, h_, w##q) \
                h_ = ((const float4*)sh_h[3])[q]; FMA4(a3, h_, w##q) }
            W_LIST(EGROW)
            #undef EGROW
            sh_g[n][0] = a0; sh_g[n][1] = a1; sh_g[n][2] = a2; sh_g[n][3] = a3;
        }
        __syncthreads();
        if (act){
            float ai = sh_g[jc][mc];
            float af = sh_g[NH + jc][mc];
            float ag = sh_g[2 * NH + jc][mc];
            float ao = sh_g[3 * NH + jc][mc];
            float ii = sigm(ai), ff = sigm(af), gg = tanh_fast(ag), oo = sigm(ao);
            c_reg = ff * c_reg + ii * gg;
            h_new = oo * tanh_fast(c_reg);
            sh_h[mc][jc] = h_new;
        }
        __syncthreads();
    }
    if (act){
        h_out[(size_t)(m0 + mc) * NH + jc] = h_new;
        c_out[(size_t)(m0 + mc) * NH + jc] = c_reg;
    }
}

// ---------------- decoder: disjoint gate/fc roles, overlapped pipeline ----------------
// 704 threads = 11 waves -> 3 waves/SIMD -> 168-VGPR cap. One set of 25 named float4
// regs overlays Wdec-row (gate threads) / fcW-row (fc threads) via a role-selected
// pointer. ~140 VGPR expected, zero scratch.

__global__ __launch_bounds__(DTH, 1) void decoder_kernel(
    const float* __restrict__ h_enc, const float* __restrict__ c_enc,
    const float* __restrict__ Whh_p, const float* __restrict__ Wdec_p,
    const float* __restrict__ b0_p,  const float* __restrict__ bdec_p,
    const float* __restrict__ fcW_p, const float* __restrict__ fcb_p,
    const float* __restrict__ trg,
    const float* __restrict__ Whh_r, const float* __restrict__ Wdec_r,
    const float* __restrict__ b0_r,  const float* __restrict__ bdec_r,
    const float* __restrict__ fcW_r, const float* __restrict__ fcb_r,
    const float* __restrict__ src,
    float* __restrict__ loss)
{
    __shared__ float sh_h[DM][104];
    __shared__ float sh_g[NG][DM + 1];    // stride 9: gcd(9,32)=1, conflict-free
    __shared__ float sh_red[11];
    const int tid = threadIdx.x;
    const int d   = (blockIdx.x >= 125) ? 1 : 0;
    const int m0  = (blockIdx.x - d * 125) * DM;
    const float* Whh  = d ? Whh_r  : Whh_p;
    const float* Wdec = d ? Wdec_r : Wdec_p;
    const float* b0   = d ? b0_r   : b0_p;
    const float* bdec = d ? bdec_r : bdec_p;
    const float* fcW  = d ? fcW_r  : fcW_p;
    const float* fcb  = d ? fcb_r  : fcb_p;
    const float* tgt  = d ? src    : trg;

    const bool gate = tid < NG;
    const bool fc   = (tid >= NG) && (tid < NG + NO);
    const int n  = gate ? tid : 0;
    const int o  = fc ? tid - NG : 0;
    const int mc = n / NH;
    const int jc = n % NH;

    // role-selected weight row -> 25 named float4 registers (overlaid across roles)
    const float4* wsrc = fc ? (const float4*)(fcW + (size_t)o * NH)
                            : (const float4*)(Wdec + (size_t)n * NH);
    W_LIST(DECLW)
    W_LIST(LOADW)
    float b0n = 0.f, bdn = 0.f, fb = 0.f;
    if (gate){ b0n = b0[n]; bdn = bdec[n]; }
    else if (fc){ fb = fcb[o]; }

    float c0 = 0.f, c1 = 0.f;
    if (gate){
        c0 = c_enc[(size_t)(m0 + mc) * NH + jc];
        c1 = c_enc[(size_t)(m0 + 4 + mc) * NH + jc];
        sh_h[mc][jc]     = h_enc[(size_t)(m0 + mc) * NH + jc];
        sh_h[mc + 4][jc] = h_enc[(size_t)(m0 + 4 + mc) * NH + jc];
    }
    float loss_acc = 0.f;
    __syncthreads();

    for (int k = 0; k <= NT; ++k){
        // ---- phase A: gate matvec (k<NT) runs concurrently with fc output (k>=1) ----
        float a0, a1, a2, a3, a4, a5, a6, a7;
        #define DGROW_V(q, wv) { float4 h_; \
            h_ = ((const float4*)sh_h[0])[q]; FMA4(a0, h_, wv) \
            h_ = ((const float4*)sh_h[1])[q]; FMA4(a1, h_, wv) \
            h_ = ((const float4*)sh_h[2])[q]; FMA4(a2, h_, wv) \
            h_ = ((const float4*)sh_h[3])[q]; FMA4(a3, h_, wv) \
            h_ = ((const float4*)sh_h[4])[q]; FMA4(a4, h_, wv) \
            h_ = ((const float4*)sh_h[5])[q]; FMA4(a5, h_, wv) \
            h_ = ((const float4*)sh_h[6])[q]; FMA4(a6, h_, wv) \
            h_ = ((const float4*)sh_h[7])[q]; FMA4(a7, h_, wv) }
        #define DGROW(q) DGROW_V(q, w##q)
        if (gate && k < NT){
            float bb = k ? bdn : b0n;
            a0=bb; a1=bb; a2=bb; a3=bb; a4=bb; a5=bb; a6=bb; a7=bb;
            if (k == 0){
                // step 0: x=0 -> plain Whh, streamed once from L2 (loop-local temp, SSA)
                const float4* whp = (const float4*)(Whh + (size_t)n * NH);
                for (int q = 0; q < 25; ++q){
                    float4 w4 = whp[q];
                    DGROW_V(q, w4)
                }
            } else {
                W_LIST(DGROW)
            }
            sh_g[n][0]=a0; sh_g[n][1]=a1; sh_g[n][2]=a2; sh_g[n][3]=a3;
            sh_g[n][4]=a4; sh_g[n][5]=a5; sh_g[n][6]=a6; sh_g[n][7]=a7;
        } else if (fc && k >= 1){
            a0=fb; a1=fb; a2=fb; a3=fb; a4=fb; a5=fb; a6=fb; a7=fb;
            W_LIST(DGROW)
            const int ti = d ? (NT - k) : (k - 1);   // pred index k-1, reversed for recon
            const float* tg = tgt + (size_t)m0 * NT * NI + (size_t)ti * NI + o;
            float df;
            df = a0 - tg[0 * NT * NI]; loss_acc += df * df;
            df = a1 - tg[1 * NT * NI]; loss_acc += df * df;
            df = a2 - tg[2 * NT * NI]; loss_acc += df * df;
            df = a3 - tg[3 * NT * NI]; loss_acc += df * df;
            df = a4 - tg[4 * NT * NI]; loss_acc += df * df;
            df = a5 - tg[5 * NT * NI]; loss_acc += df * df;
            df = a6 - tg[6 * NT * NI]; loss_acc += df * df;
            df = a7 - tg[7 * NT * NI]; loss_acc += df * df;
        }
        #undef DGROW
        #undef DGROW_V
        __syncthreads();
        // ---- phase B: nonlinearity + h update ----
        if (gate && k < NT){
            {   // pair (mc, jc)
                float ai = sh_g[jc][mc], af = sh_g[NH + jc][mc];
                float ag = sh_g[2 * NH + jc][mc], ao = sh_g[3 * NH + jc][mc];
                float ii = sigm(ai), ff = sigm(af), gg = tanh_fast(ag), oo = sigm(ao);
                c0 = ff * c0 + ii * gg;
                sh_h[mc][jc] = oo * tanh_fast(c0);
            }
            {   // pair (mc+4, jc)
                float ai = sh_g[jc][mc + 4], af = sh_g[NH + jc][mc + 4];
                float ag = sh_g[2 * NH + jc][mc + 4], ao = sh_g[3 * NH + jc][mc + 4];
                float ii = sigm(ai), ff = sigm(af), gg = tanh_fast(ag), oo = sigm(ao);
                c1 = ff * c1 + ii * gg;
                sh_h[mc + 4][jc] = oo * tanh_fast(c1);
            }
        }
        __syncthreads();
    }

    // block loss reduction -> one atomic per block
    for (int off = 32; off > 0; off >>= 1) loss_acc += __shfl_down(loss_acc, off);
    if ((tid & 63) == 0) sh_red[tid >> 6] = loss_acc;
    __syncthreads();
    if (tid == 0){
        float s = 0.f;
        for (int w = 0; w < 11; ++w) s += sh_red[w];
        atomicAdd(&loss[d], s);
    }
}

__global__ void finalize_kernel(const float* __restrict__ loss, float* __restrict__ out){
    if (threadIdx.x == 0){
        const float inv = 1.f / 26400000.f;   // B*T*O
        out[0] = loss[1] * inv;   // reconstruct_loss
        out[1] = loss[0] * inv;   // predict_loss
    }
}

extern "C" void kernel_launch(void* const* d_in, const int* in_sizes, int n_in,
                              void* d_out, int out_size, void* d_ws, size_t ws_size,
                              hipStream_t stream)
{
    const float* src  = (const float*)d_in[0];
    const float* trg  = (const float*)d_in[1];
    const float* eWih = (const float*)d_in[2];
    const float* eWhh = (const float*)d_in[3];
    const float* ebih = (const float*)d_in[4];
    const float* ebhh = (const float*)d_in[5];
    const float* pWih = (const float*)d_in[6];
    const float* pWhh = (const float*)d_in[7];
    const float* pbih = (const float*)d_in[8];
    const float* pbhh = (const float*)d_in[9];
    const float* pfcW = (const float*)d_in[10];
    const float* pfcb = (const float*)d_in[11];
    const float* rWih = (const float*)d_in[12];
    const float* rWhh = (const float*)d_in[13];
    const float* rbih = (const float*)d_in[14];
    const float* rbhh = (const float*)d_in[15];
    const float* rfcW = (const float*)d_in[16];
    const float* rfcb = (const float*)d_in[17];

    float* w      = (float*)d_ws;           // total 387,602 floats (~1.55 MB)
    float* Wih4   = w;                      // 105600
    float* Wdec_p = w + 105600;             // 40000
    float* Wdec_r = w + 145600;             // 40000
    float* b0_p   = w + 185600;             // 400
    float* bdec_p = w + 186000;             // 400
    float* b0_r   = w + 186400;             // 400
    float* bdec_r = w + 186800;             // 400
    float* bcat   = w + 187200;             // 400
    float* h_enc  = w + 187600;             // 100000
    float* c_enc  = w + 287600;             // 100000
    float* loss   = w + 387600;             // 2

    prep_enc<<<(NG * NI + 255) / 256, 256, 0, stream>>>(eWih, ebih, ebhh, Wih4, bcat);
    prep_wdec<<<(NG * NH + 255) / 256, 256, 0, stream>>>(pWih, pWhh, pfcW, Wdec_p);
    prep_wdec<<<(NG * NH + 255) / 256, 256, 0, stream>>>(rWih, rWhh, rfcW, Wdec_r);
    prep_bias<<<4, 256, 0, stream>>>(pbih, pbhh, pWih, pfcb, rbih, rbhh, rWih, rfcb,
                                     b0_p, bdec_p, b0_r, bdec_r, loss);
    encoder_kernel<<<250, 512, 0, stream>>>(src, Wih4, eWhh, bcat, h_enc, c_enc);
    decoder_kernel<<<250, DTH, 0, stream>>>(h_enc, c_enc,
        pWhh, Wdec_p, b0_p, bdec_p, pfcW, pfcb, trg,
        rWhh, Wdec_r, b0_r, bdec_r, rfcW, rfcb, src,
        loss);
    finalize_kernel<<<1, 64, 0, stream>>>(loss, (float*)d_out);
}

// Round 6
// 2761.855 us; speedup vs baseline: 1.8965x; 1.8965x over previous
//
#include <hip/hip_runtime.h>
#include <math.h>

#define NB 1000
#define NT 100
#define NI 264
#define NH 100
#define NO 264
#define NG 400          // 4*NH
#define KE 364          // NI + NH (fallback combined K)
#define DM 8            // decoder rows per block (125 blocks per decoder)
#define DTH 704         // decoder threads: 0-399 gate, 400-663 fc, 664-703 idle
#define XM 16           // xp rows per block

__device__ __forceinline__ float sigm(float x){ return 1.f / (1.f + __expf(-x)); }
__device__ __forceinline__ float tanh_fast(float x){
    float e = __expf(-2.f * x);
    return 2.f / (1.f + e) - 1.f;
}

// param names must never collide with member tokens .x/.y/.z/.w
#define FMA4(acc, hv, wv) acc += hv.x*wv.x + hv.y*wv.y + hv.z*wv.z + hv.w*wv.w;

// ---------------- prep kernels ----------------

// generic k4-major transpose: out[(k4*N + n)*4 + j] = in[n*K + 4*k4 + j]
__global__ void prep_T4(const float* __restrict__ in, float* __restrict__ out, int N, int K)
{
    int idx = blockIdx.x * 256 + threadIdx.x;
    if (idx >= N * K) return;
    int j  = idx & 3;
    int n  = (idx >> 2) % N;
    int k  = (idx / (4 * N)) * 4 + j;
    out[idx] = in[n * K + k];
}

// fallback: combined [Wih | Whh] transposed k4-major (K = 364)
__global__ void prep_encT(const float* __restrict__ Wih, const float* __restrict__ Whh,
                          float* __restrict__ out)
{
    int idx = blockIdx.x * 256 + threadIdx.x;
    if (idx >= NG * KE) return;
    int j  = idx & 3;
    int n  = (idx >> 2) % NG;
    int k  = (idx / (4 * NG)) * 4 + j;
    out[idx] = (k < NI) ? Wih[n * NI + k] : Whh[n * NH + (k - NI)];
}

// WdecT4[(k4*NG+n)*4 + k&3] = Whh[n][k] + sum_o Wih[n][o]*fcW[o][k]  (feedback folded, transposed)
__global__ void prep_wdec(const float* __restrict__ Wih, const float* __restrict__ Whh,
                          const float* __restrict__ fcW, float* __restrict__ WdecT)
{
    int idx = blockIdx.x * 256 + threadIdx.x;
    if (idx >= NG * NH) return;
    int n = idx / NH, k = idx - n * NH;
    float acc = Whh[idx];
    const float* wr = Wih + (size_t)n * NI;
    for (int o = 0; o < NI; ++o) acc = fmaf(wr[o], fcW[o * NH + k], acc);
    WdecT[((k >> 2) * NG + n) * 4 + (k & 3)] = acc;
}

// b0 = bih+bhh ; bdec = b0 + Wih @ fcb ; bcat = enc bih+bhh ; zero loss
__global__ void prep_bias(const float* __restrict__ pb1, const float* __restrict__ pb2,
                          const float* __restrict__ pW,  const float* __restrict__ pfb,
                          const float* __restrict__ rb1, const float* __restrict__ rb2,
                          const float* __restrict__ rW,  const float* __restrict__ rfb,
                          const float* __restrict__ eb1, const float* __restrict__ eb2,
                          float* __restrict__ b0_p, float* __restrict__ bdec_p,
                          float* __restrict__ b0_r, float* __restrict__ bdec_r,
                          float* __restrict__ bcat, float* __restrict__ loss)
{
    int tid = blockIdx.x * 256 + threadIdx.x;
    if (tid < 2) loss[tid] = 0.f;
    if (tid < NG) bcat[tid] = eb1[tid] + eb2[tid];
    if (tid >= 2 * NG) return;
    int dd = tid / NG, n = tid - dd * NG;
    const float* b1 = dd ? rb1 : pb1;
    const float* b2 = dd ? rb2 : pb2;
    const float* W  = dd ? rW  : pW;
    const float* fb = dd ? rfb : pfb;
    float base = b1[n] + b2[n];
    float acc = base;
    const float* wr = W + (size_t)n * NI;
    for (int o = 0; o < NI; ++o) acc = fmaf(wr[o], fb[o], acc);
    if (dd){ b0_r[n] = base; bdec_r[n] = acc; }
    else   { b0_p[n] = base; bdec_p[n] = acc; }
}

// ---------------- XP: batched x-projection XP[bt][n] = src[bt] . Wih[n] ----------------

__global__ __launch_bounds__(512) void xp_kernel(const float* __restrict__ src,
                                                 const float4* __restrict__ WihT4,
                                                 float* __restrict__ xp)
{
    __shared__ float sh_x[XM * NI];   // 16.5 KB
    __shared__ float sh_o[XM * NG];   // 25.6 KB
    const int tid = threadIdx.x;
    const size_t bt0 = (size_t)blockIdx.x * XM;
    for (int i = tid; i < XM * NI; i += 512) sh_x[i] = src[bt0 * NI + i];
    __syncthreads();
    const bool act = tid < NG;
    const int n = act ? tid : 0;
    float a0=0,a1=0,a2=0,a3=0,a4=0,a5=0,a6=0,a7=0,
          a8=0,a9=0,a10=0,a11=0,a12=0,a13=0,a14=0,a15=0;
    if (act){
        #pragma unroll 3
        for (int k4 = 0; k4 < NI / 4; ++k4){
            float4 wq = WihT4[k4 * NG + n];
            float4 hq;
            #define XROW(r, acc) hq = ((const float4*)(sh_x + (r) * NI))[k4]; FMA4(acc, hq, wq)
            XROW(0,a0)  XROW(1,a1)  XROW(2,a2)  XROW(3,a3)
            XROW(4,a4)  XROW(5,a5)  XROW(6,a6)  XROW(7,a7)
            XROW(8,a8)  XROW(9,a9)  XROW(10,a10) XROW(11,a11)
            XROW(12,a12) XROW(13,a13) XROW(14,a14) XROW(15,a15)
            #undef XROW
        }
        sh_o[0*NG+n]=a0;   sh_o[1*NG+n]=a1;   sh_o[2*NG+n]=a2;   sh_o[3*NG+n]=a3;
        sh_o[4*NG+n]=a4;   sh_o[5*NG+n]=a5;   sh_o[6*NG+n]=a6;   sh_o[7*NG+n]=a7;
        sh_o[8*NG+n]=a8;   sh_o[9*NG+n]=a9;   sh_o[10*NG+n]=a10; sh_o[11*NG+n]=a11;
        sh_o[12*NG+n]=a12; sh_o[13*NG+n]=a13; sh_o[14*NG+n]=a14; sh_o[15*NG+n]=a15;
    }
    __syncthreads();
    for (int i = tid; i < XM * NG; i += 512) xp[bt0 * NG + i] = sh_o[i];
}

// 8-row FMA group against sh_h rows at float4 index k4 (uses a0..a7 from scope)
#define ROW8(wq) { float4 hq; \
    hq = ((const float4*)sh_h[0])[k4]; FMA4(a0, hq, wq) \
    hq = ((const float4*)sh_h[1])[k4]; FMA4(a1, hq, wq) \
    hq = ((const float4*)sh_h[2])[k4]; FMA4(a2, hq, wq) \
    hq = ((const float4*)sh_h[3])[k4]; FMA4(a3, hq, wq) \
    hq = ((const float4*)sh_h[4])[k4]; FMA4(a4, hq, wq) \
    hq = ((const float4*)sh_h[5])[k4]; FMA4(a5, hq, wq) \
    hq = ((const float4*)sh_h[6])[k4]; FMA4(a6, hq, wq) \
    hq = ((const float4*)sh_h[7])[k4]; FMA4(a7, hq, wq) }

// ---------------- encoder recurrence (big-ws path): 8 rows/block, 125 blocks ----------------

__global__ __launch_bounds__(512) void enc_rec(const float* __restrict__ xp,
                                               const float4* __restrict__ WhhT4,
                                               const float* __restrict__ bcat,
                                               float* __restrict__ h_out, float* __restrict__ c_out)
{
    __shared__ float sh_h[DM][104];
    __shared__ float sh_g[NG][DM + 1];
    const int tid = threadIdx.x;
    const int b0  = blockIdx.x * DM;
    const bool act = tid < NG;
    const int n  = act ? tid : 0;
    const int mc = n / NH, jc = n % NH;
    float bias = act ? bcat[n] : 0.f;
    float c0 = 0.f, c1 = 0.f;
    if (act){ sh_h[mc][jc] = 0.f; sh_h[mc + 4][jc] = 0.f; }
    __syncthreads();

    for (int t = 0; t < NT; ++t){
        if (act){
            const float* xr = xp + ((size_t)b0 * NT + t) * NG + n;
            float a0 = bias + xr[0 * NT * NG];
            float a1 = bias + xr[1 * NT * NG];
            float a2 = bias + xr[2 * NT * NG];
            float a3 = bias + xr[3 * NT * NG];
            float a4 = bias + xr[4 * NT * NG];
            float a5 = bias + xr[5 * NT * NG];
            float a6 = bias + xr[6 * NT * NG];
            float a7 = bias + xr[7 * NT * NG];
            #pragma unroll 5
            for (int k4 = 0; k4 < NH / 4; ++k4){
                float4 wq = WhhT4[k4 * NG + n];
                ROW8(wq)
            }
            sh_g[n][0]=a0; sh_g[n][1]=a1; sh_g[n][2]=a2; sh_g[n][3]=a3;
            sh_g[n][4]=a4; sh_g[n][5]=a5; sh_g[n][6]=a6; sh_g[n][7]=a7;
        }
        __syncthreads();
        if (act){
            {   float ai = sh_g[jc][mc], af = sh_g[NH + jc][mc];
                float ag = sh_g[2*NH + jc][mc], ao = sh_g[3*NH + jc][mc];
                float ii = sigm(ai), ff = sigm(af), gg = tanh_fast(ag), oo = sigm(ao);
                c0 = ff * c0 + ii * gg;
                sh_h[mc][jc] = oo * tanh_fast(c0);
            }
            {   float ai = sh_g[jc][mc+4], af = sh_g[NH + jc][mc+4];
                float ag = sh_g[2*NH + jc][mc+4], ao = sh_g[3*NH + jc][mc+4];
                float ii = sigm(ai), ff = sigm(af), gg = tanh_fast(ag), oo = sigm(ao);
                c1 = ff * c1 + ii * gg;
                sh_h[mc + 4][jc] = oo * tanh_fast(c1);
            }
        }
        __syncthreads();
    }
    if (act){
        h_out[(size_t)(b0 + mc) * NH + jc]     = sh_h[mc][jc];
        c_out[(size_t)(b0 + mc) * NH + jc]     = c0;
        h_out[(size_t)(b0 + 4 + mc) * NH + jc] = sh_h[mc + 4][jc];
        c_out[(size_t)(b0 + 4 + mc) * NH + jc] = c1;
    }
}

// ---------------- encoder (fallback, small ws): stream combined WencT4, 4 rows/block ----------------

__global__ __launch_bounds__(512) void enc_stream(const float* __restrict__ src,
                                                  const float4* __restrict__ WencT4,
                                                  const float* __restrict__ bcat,
                                                  float* __restrict__ h_out, float* __restrict__ c_out)
{
    __shared__ float sh_xh[4][368];   // [0,264)=x, [264,364)=h
    __shared__ float sh_g[NG][5];
    const int tid = threadIdx.x;
    const int m0  = blockIdx.x * 4;
    const bool act = tid < NG;
    const int n  = act ? tid : 0;
    const int mc = n / NH, jc = n % NH;
    float bias = act ? bcat[n] : 0.f;
    float c_reg = 0.f, h_new = 0.f;
    if (act) sh_xh[mc][NI + jc] = 0.f;
    const float* s0 = src + (size_t)m0 * NT * NI;

    for (int t = 0; t < NT; ++t){
        for (int i = tid; i < 4 * NI; i += 512){
            int r = i / NI, k = i - r * NI;
            sh_xh[r][k] = s0[(size_t)r * NT * NI + (size_t)t * NI + k];
        }
        __syncthreads();
        if (act){
            float a0 = bias, a1 = bias, a2 = bias, a3 = bias;
            #pragma unroll 7
            for (int k4 = 0; k4 < KE / 4; ++k4){
                float4 wq = WencT4[k4 * NG + n];
                float4 hq;
                hq = ((const float4*)sh_xh[0])[k4]; FMA4(a0, hq, wq)
                hq = ((const float4*)sh_xh[1])[k4]; FMA4(a1, hq, wq)
                hq = ((const float4*)sh_xh[2])[k4]; FMA4(a2, hq, wq)
                hq = ((const float4*)sh_xh[3])[k4]; FMA4(a3, hq, wq)
            }
            sh_g[n][0]=a0; sh_g[n][1]=a1; sh_g[n][2]=a2; sh_g[n][3]=a3;
        }
        __syncthreads();
        if (act){
            float ai = sh_g[jc][mc], af = sh_g[NH + jc][mc];
            float ag = sh_g[2*NH + jc][mc], ao = sh_g[3*NH + jc][mc];
            float ii = sigm(ai), ff = sigm(af), gg = tanh_fast(ag), oo = sigm(ao);
            c_reg = ff * c_reg + ii * gg;
            h_new = oo * tanh_fast(c_reg);
            sh_xh[mc][NI + jc] = h_new;
        }
        __syncthreads();
    }
    if (act){
        h_out[(size_t)(m0 + mc) * NH + jc] = h_new;
        c_out[(size_t)(m0 + mc) * NH + jc] = c_reg;
    }
}

// ---------------- decoder: L2-streamed coalesced weights, gate/fc roles overlapped ----------------

__global__ __launch_bounds__(DTH) void decoder_kernel(
    const float* __restrict__ h_enc, const float* __restrict__ c_enc,
    const float4* __restrict__ WhhT_p, const float4* __restrict__ WdecT_p,
    const float* __restrict__ b0_p,  const float* __restrict__ bdec_p,
    const float4* __restrict__ fcWT_p, const float* __restrict__ fcb_p,
    const float* __restrict__ trg,
    const float4* __restrict__ WhhT_r, const float4* __restrict__ WdecT_r,
    const float* __restrict__ b0_r,  const float* __restrict__ bdec_r,
    const float4* __restrict__ fcWT_r, const float* __restrict__ fcb_r,
    const float* __restrict__ src,
    float* __restrict__ loss)
{
    __shared__ float sh_h[DM][104];
    __shared__ float sh_g[NG][DM + 1];
    __shared__ float sh_red[11];
    const int tid = threadIdx.x;
    const int d   = (blockIdx.x >= 125) ? 1 : 0;
    const int m0  = (blockIdx.x - d * 125) * DM;
    const float4* WhhT  = d ? WhhT_r  : WhhT_p;
    const float4* WdecT = d ? WdecT_r : WdecT_p;
    const float*  b0    = d ? b0_r    : b0_p;
    const float*  bdec  = d ? bdec_r  : bdec_p;
    const float4* fcWT  = d ? fcWT_r  : fcWT_p;
    const float*  fcb   = d ? fcb_r   : fcb_p;
    const float*  tgt   = d ? src     : trg;

    const bool gate = tid < NG;
    const bool fc   = (tid >= NG) && (tid < NG + NO);
    const int n  = gate ? tid : 0;
    const int o  = fc ? tid - NG : 0;
    const int mc = n / NH, jc = n % NH;

    float b0n = 0.f, bdn = 0.f, fb = 0.f;
    if (gate){ b0n = b0[n]; bdn = bdec[n]; }
    else if (fc){ fb = fcb[o]; }

    float c0 = 0.f, c1 = 0.f;
    if (gate){
        c0 = c_enc[(size_t)(m0 + mc) * NH + jc];
        c1 = c_enc[(size_t)(m0 + 4 + mc) * NH + jc];
        sh_h[mc][jc]     = h_enc[(size_t)(m0 + mc) * NH + jc];
        sh_h[mc + 4][jc] = h_enc[(size_t)(m0 + 4 + mc) * NH + jc];
    }
    float loss_acc = 0.f;
    __syncthreads();

    for (int k = 0; k <= NT; ++k){
        float a0, a1, a2, a3, a4, a5, a6, a7;
        if (gate && k < NT){
            const float4* WT = (k == 0) ? WhhT : WdecT;   // step 0: x=0 -> plain Whh
            float bb = k ? bdn : b0n;
            a0=bb; a1=bb; a2=bb; a3=bb; a4=bb; a5=bb; a6=bb; a7=bb;
            #pragma unroll 5
            for (int k4 = 0; k4 < NH / 4; ++k4){
                float4 wq = WT[k4 * NG + n];   // lane n -> consecutive float4: coalesced, L2-shared
                ROW8(wq)
            }
            sh_g[n][0]=a0; sh_g[n][1]=a1; sh_g[n][2]=a2; sh_g[n][3]=a3;
            sh_g[n][4]=a4; sh_g[n][5]=a5; sh_g[n][6]=a6; sh_g[n][7]=a7;
        } else if (fc && k >= 1){
            a0=fb; a1=fb; a2=fb; a3=fb; a4=fb; a5=fb; a6=fb; a7=fb;
            #pragma unroll 5
            for (int k4 = 0; k4 < NH / 4; ++k4){
                float4 wq = fcWT[k4 * NO + o];
                ROW8(wq)
            }
            const int ti = d ? (NT - k) : (k - 1);   // pred index k-1, reversed for recon
            const float* tg = tgt + (size_t)m0 * NT * NI + (size_t)ti * NI + o;
            float df;
            df = a0 - tg[0 * NT * NI]; loss_acc += df * df;
            df = a1 - tg[1 * NT * NI]; loss_acc += df * df;
            df = a2 - tg[2 * NT * NI]; loss_acc += df * df;
            df = a3 - tg[3 * NT * NI]; loss_acc += df * df;
            df = a4 - tg[4 * NT * NI]; loss_acc += df * df;
            df = a5 - tg[5 * NT * NI]; loss_acc += df * df;
            df = a6 - tg[6 * NT * NI]; loss_acc += df * df;
            df = a7 - tg[7 * NT * NI]; loss_acc += df * df;
        }
        __syncthreads();
        if (gate && k < NT){
            {   float ai = sh_g[jc][mc], af = sh_g[NH + jc][mc];
                float ag = sh_g[2*NH + jc][mc], ao = sh_g[3*NH + jc][mc];
                float ii = sigm(ai), ff = sigm(af), gg = tanh_fast(ag), oo = sigm(ao);
                c0 = ff * c0 + ii * gg;
                sh_h[mc][jc] = oo * tanh_fast(c0);
            }
            {   float ai = sh_g[jc][mc+4], af = sh_g[NH + jc][mc+4];
                float ag = sh_g[2*NH + jc][mc+4], ao = sh_g[3*NH + jc][mc+4];
                float ii = sigm(ai), ff = sigm(af), gg = tanh_fast(ag), oo = sigm(ao);
                c1 = ff * c1 + ii * gg;
                sh_h[mc + 4][jc] = oo * tanh_fast(c1);
            }
        }
        __syncthreads();
    }

    for (int off = 32; off > 0; off >>= 1) loss_acc += __shfl_down(loss_acc, off);
    if ((tid & 63) == 0) sh_red[tid >> 6] = loss_acc;
    __syncthreads();
    if (tid == 0){
        float s = 0.f;
        for (int w = 0; w < 11; ++w) s += sh_red[w];
        atomicAdd(&loss[d], s);
    }
}

__global__ void finalize_kernel(const float* __restrict__ loss, float* __restrict__ out){
    if (threadIdx.x == 0){
        const float inv = 1.f / 26400000.f;   // B*T*O
        out[0] = loss[1] * inv;   // reconstruct_loss
        out[1] = loss[0] * inv;   // predict_loss
    }
}

extern "C" void kernel_launch(void* const* d_in, const int* in_sizes, int n_in,
                              void* d_out, int out_size, void* d_ws, size_t ws_size,
                              hipStream_t stream)
{
    const float* src  = (const float*)d_in[0];
    const float* trg  = (const float*)d_in[1];
    const float* eWih = (const float*)d_in[2];
    const float* eWhh = (const float*)d_in[3];
    const float* ebih = (const float*)d_in[4];
    const float* ebhh = (const float*)d_in[5];
    const float* pWih = (const float*)d_in[6];
    const float* pWhh = (const float*)d_in[7];
    const float* pbih = (const float*)d_in[8];
    const float* pbhh = (const float*)d_in[9];
    const float* pfcW = (const float*)d_in[10];
    const float* pfcb = (const float*)d_in[11];
    const float* rWih = (const float*)d_in[12];
    const float* rWhh = (const float*)d_in[13];
    const float* rbih = (const float*)d_in[14];
    const float* rbhh = (const float*)d_in[15];
    const float* rfcW = (const float*)d_in[16];
    const float* rfcb = (const float*)d_in[17];

    float* w       = (float*)d_ws;
    float* WihT4e  = w;                 // 105600
    float* WencT4  = w + 105600;        // 145600 (fallback)
    float* WhhT4e  = w + 251200;        // 40000
    float* WdT_p   = w + 291200;        // 40000
    float* WdT_r   = w + 331200;        // 40000
    float* WhT_p   = w + 371200;        // 40000
    float* WhT_r   = w + 411200;        // 40000
    float* fcT_p   = w + 451200;        // 26400
    float* fcT_r   = w + 477600;        // 26400
    float* b0_p    = w + 504000;        // 400
    float* bdec_p  = w + 504400;        // 400
    float* b0_r    = w + 504800;        // 400
    float* bdec_r  = w + 505200;        // 400
    float* bcat    = w + 505600;        // 400
    float* h_enc   = w + 506000;        // 100000
    float* c_enc   = w + 606000;        // 100000
    float* loss    = w + 706000;        // 2
    float* XP      = w + 706016;        // 40,000,000 (big path only)
    const bool big = ws_size >= (size_t)(706016 + 40000000) * 4;

    const int TB = 256;
    if (big){
        prep_T4<<<(NG*NI + TB-1)/TB, TB, 0, stream>>>(eWih, WihT4e, NG, NI);
        prep_T4<<<(NG*NH + TB-1)/TB, TB, 0, stream>>>(eWhh, WhhT4e, NG, NH);
    } else {
        prep_encT<<<(NG*KE + TB-1)/TB, TB, 0, stream>>>(eWih, eWhh, WencT4);
    }
    prep_T4<<<(NG*NH + TB-1)/TB, TB, 0, stream>>>(pWhh, WhT_p, NG, NH);
    prep_T4<<<(NG*NH + TB-1)/TB, TB, 0, stream>>>(rWhh, WhT_r, NG, NH);
    prep_T4<<<(NO*NH + TB-1)/TB, TB, 0, stream>>>(pfcW, fcT_p, NO, NH);
    prep_T4<<<(NO*NH + TB-1)/TB, TB, 0, stream>>>(rfcW, fcT_r, NO, NH);
    prep_wdec<<<(NG*NH + TB-1)/TB, TB, 0, stream>>>(pWih, pWhh, pfcW, WdT_p);
    prep_wdec<<<(NG*NH + TB-1)/TB, TB, 0, stream>>>(rWih, rWhh, rfcW, WdT_r);
    prep_bias<<<4, TB, 0, stream>>>(pbih, pbhh, pWih, pfcb, rbih, rbhh, rWih, rfcb,
                                    ebih, ebhh, b0_p, bdec_p, b0_r, bdec_r, bcat, loss);

    if (big){
        xp_kernel<<<(NB*NT)/XM, 512, 0, stream>>>(src, (const float4*)WihT4e, XP);
        enc_rec<<<NB/DM, 512, 0, stream>>>(XP, (const float4*)WhhT4e, bcat, h_enc, c_enc);
    } else {
        enc_stream<<<NB/4, 512, 0, stream>>>(src, (const float4*)WencT4, bcat, h_enc, c_enc);
    }
    decoder_kernel<<<250, DTH, 0, stream>>>(h_enc, c_enc,
        (const float4*)WhT_p, (const float4*)WdT_p, b0_p, bdec_p, (const float4*)fcT_p, pfcb, trg,
        (const float4*)WhT_r, (const float4*)WdT_r, b0_r, bdec_r, (const float4*)fcT_r, rfcb, src,
        loss);
    finalize_kernel<<<1, 64, 0, stream>>>(loss, (float*)d_out);
}